// Round 1
// baseline (594.250 us; speedup 1.0000x reference)
//
#include <hip/hip_runtime.h>
#include <math.h>

// GaussianLayer: per row (B=524288): mu=x[0], sigma=exp(0.5*x[1]);
// pdf over xx=-99..99, then cumsum along bins (199). Output (B,199) fp32.
//
// Write-bound kernel (~417 MB out). Strategy:
//  - 1 thread per row computes the serial cumsum (199 bins, 4 x 32/7-bin chunks)
//  - chunks staged in LDS (stride 33 floats -> bank-conflict-free both phases)
//  - block-cooperative transposed write: each wave stores 128B-contiguous runs

#define ROWS 256   // rows per block == block size
#define CW   32    // chunk width (bins per staging pass)
#define LSTR 33    // LDS row stride (+1 padding)

__global__ __launch_bounds__(256)
void gauss_cdf_kernel(const float2* __restrict__ x, float* __restrict__ out, int B) {
    __shared__ float lds[ROWS * LSTR];
    const int tid     = threadIdx.x;
    const int rowBase = blockIdx.x * ROWS;
    const int row     = rowBase + tid;

    float mu = 0.f, coefA = 0.f, inv_norm = 0.f;
    if (row < B) {
        float2 v = x[row];
        mu = v.x;
        // s = 1/sigma = exp(-0.5*logvar)
        float s  = __expf(-0.5f * v.y);
        inv_norm = 0.3989422804014327f * s;   // 1/(sigma*sqrt(2*pi))
        coefA    = -0.5f * s * s;             // -1/(2*sigma^2)
    }

    float acc = 0.f;
    float* outBase = out + (size_t)rowBase * 199;

    // bins 0..191 in six 32-wide chunks
    #pragma unroll 1
    for (int c0 = 0; c0 < 192; c0 += CW) {
        #pragma unroll
        for (int j = 0; j < CW; ++j) {
            float t = (float)(c0 + j - 99) - mu;
            acc += inv_norm * __expf(coefA * t * t);
            lds[tid * LSTR + j] = acc;
        }
        __syncthreads();
        // cooperative transposed write: ROWS*CW elements, 256 threads
        #pragma unroll
        for (int k = 0; k < CW; ++k) {
            int i = tid + (k << 8);        // k*256
            int r = i >> 5;                // i / CW
            int c = i & 31;                // i % CW
            if (rowBase + r < B)
                outBase[r * 199 + c0 + c] = lds[r * LSTR + c];
        }
        __syncthreads();
    }

    // last chunk: bins 192..198 (7 bins)
    #pragma unroll
    for (int j = 0; j < 7; ++j) {
        float t = (float)(192 + j - 99) - mu;
        acc += inv_norm * __expf(coefA * t * t);
        lds[tid * LSTR + j] = acc;
    }
    __syncthreads();
    for (int i = tid; i < ROWS * 7; i += 256) {
        int r = i / 7;
        int c = i - r * 7;
        if (rowBase + r < B)
            outBase[r * 199 + 192 + c] = lds[r * LSTR + c];
    }
}

extern "C" void kernel_launch(void* const* d_in, const int* in_sizes, int n_in,
                              void* d_out, int out_size, void* d_ws, size_t ws_size,
                              hipStream_t stream) {
    const float2* x = (const float2*)d_in[0];
    float* out = (float*)d_out;
    const int B = in_sizes[0] / 2;               // (B,2) fp32 input
    const int grid = (B + ROWS - 1) / ROWS;      // 2048 blocks
    gauss_cdf_kernel<<<grid, 256, 0, stream>>>(x, out, B);
}

// Round 2
// 411.932 us; speedup vs baseline: 1.4426x; 1.4426x over previous
//
#include <hip/hip_runtime.h>
#include <math.h>

// GaussianLayer: per row (B=524288): mu=x[0], sigma=exp(0.5*x[1]);
// pdf over xx=-99..99, cumsum over 199 bins. Output (B,199) fp32 = 417 MB.
//
// Write-bound. Design: 64 rows/block staged FULLY in LDS (flat, == output
// layout), 4 waves x 64 lanes; wave q computes quarter q of every row's
// cumsum (serial chain split via a totals-array fixup). Then a single
// barrier and one fully-contiguous 16B-aligned float4 sweep to global.
// No global store is issued before any barrier -> no vmcnt(0) drain stalls;
// store drain overlaps the next block's compute (3 blocks/CU resident).

#define ROWS     64
#define NB       199
#define NTHREADS 256

__global__ __launch_bounds__(NTHREADS)
void gauss_cdf_kernel(const float2* __restrict__ x, float* __restrict__ out, int B) {
    __shared__ __align__(16) float lds[ROWS * NB];  // 50,944 B, flat == out layout
    __shared__ float tot[4 * ROWS];                 // per-quarter local totals

    const int tid = threadIdx.x;
    const int r   = tid & 63;        // row within block (lane id)
    const int q   = tid >> 6;        // quarter index (wave id)
    const int rowBase = blockIdx.x * ROWS;
    const int row = rowBase + r;

    float mu = 0.f, coefA = 0.f, inv_norm = 0.f;
    if (row < B) {
        float2 v = x[row];
        mu = v.x;
        float s  = __expf(-0.5f * v.y);        // 1/sigma
        inv_norm = 0.3989422804014327f * s;    // 1/(sigma*sqrt(2pi))
        coefA    = -0.5f * s * s;              // -1/(2 sigma^2)
    }

    const int qstart = q * 50;
    const int qlen   = (q == 3) ? 49 : 50;

    // phase 1: local cumsum of this quarter (stride-199 LDS: 2-way, free)
    float acc = 0.f;
    float* rowLds = lds + r * NB + qstart;
    #pragma unroll 5
    for (int j = 0; j < qlen; ++j) {
        float t = (float)(qstart + j - 99) - mu;
        acc += inv_norm * __expf(coefA * t * t);
        rowLds[j] = acc;
    }
    tot[q * ROWS + r] = acc;
    __syncthreads();

    // phase 2: add prefix of earlier quarters' totals (race-free: tot[] is
    // written only in phase 1)
    if (q > 0) {
        float base = tot[r];
        if (q > 1) base += tot[ROWS + r];
        if (q > 2) base += tot[2 * ROWS + r];
        #pragma unroll 5
        for (int j = 0; j < qlen; ++j) rowLds[j] += base;
    }
    __syncthreads();

    // phase 3: contiguous float4 sweep of the block's 64x199 region.
    // Region byte offset = blockIdx * 50,944 (16B aligned). Linear
    // ds_read_b128 is bank-conflict-free.
    if (rowBase + ROWS <= B) {
        const float4* src = reinterpret_cast<const float4*>(lds);
        float4* dst = reinterpret_cast<float4*>(out + (size_t)rowBase * NB);
        #pragma unroll 1
        for (int i = tid; i < (ROWS * NB) / 4; i += NTHREADS)
            dst[i] = src[i];
    } else {  // generic tail (unused for B=524288)
        for (int i = tid; i < ROWS * NB; i += NTHREADS) {
            int rr = i / NB;
            if (rowBase + rr < B) out[(size_t)rowBase * NB + i] = lds[i];
        }
    }
}

extern "C" void kernel_launch(void* const* d_in, const int* in_sizes, int n_in,
                              void* d_out, int out_size, void* d_ws, size_t ws_size,
                              hipStream_t stream) {
    const float2* x = (const float2*)d_in[0];
    float* out = (float*)d_out;
    const int B = in_sizes[0] / 2;                  // (B,2) fp32
    const int grid = (B + ROWS - 1) / ROWS;         // 8192 blocks
    gauss_cdf_kernel<<<grid, NTHREADS, 0, stream>>>(x, out, B);
}